// Round 5
// baseline (35.522 us; speedup 1.0000x reference)
//
#include <hip/hip_runtime.h>
#include <hip/hip_fp16.h>
#include <math.h>

#define N_PTS 512
#define W_IMG 256
#define H_IMG 256
#define NPIX (W_IMG * H_IMG)
#define NSEG 8
#define SEG_LEN (N_PTS / NSEG)   // 64

// ws layout, interleaved 32 B per point (rank-sorted by depth):
//   rec[2n]   = (U f32, V f32, h2(A',B'), PT f32)
//   rec[2n+1] = (C' f32, h2(R,G), h2(Bc,AL), D f32)
// with A' = -0.5a, B' = -b, C' = -0.5c, PT = -log(255*AL) - 0.02

__device__ inline float pack2h(float a, float b) {
    __half2 h = __halves2half2(__float2half(a), __float2half(b));
    float f; __builtin_memcpy(&f, &h, 4); return f;
}
__device__ inline float2 unp2h(float v) {
    __half2 h; __builtin_memcpy(&h, &v, 4);
    return __half22float2(h);                  // (lo, hi)
}

__global__ __launch_bounds__(N_PTS) void prep_kernel(
    const float* __restrict__ pc,      // N x 3
    const float* __restrict__ q,       // 1 x 4  (x,y,z,w)
    const float* __restrict__ t,       // 1 x 3
    const float* __restrict__ K,       // 3 x 3 row-major
    const float* __restrict__ color,   // N x 3
    const float* __restrict__ alpha,   // N
    const float* __restrict__ conic,   // N x 3 (a,b,c)
    float4* __restrict__ ws4)
{
    __shared__ float sd[N_PTS];
    const int tid = threadIdx.x;

    const float qx = q[0], qy = q[1], qz = q[2], qw = q[3];
    const float R00 = 1.f - 2.f * (qy * qy + qz * qz);
    const float R01 = 2.f * (qx * qy - qz * qw);
    const float R02 = 2.f * (qx * qz + qy * qw);
    const float R10 = 2.f * (qx * qy + qz * qw);
    const float R11 = 1.f - 2.f * (qx * qx + qz * qz);
    const float R12 = 2.f * (qy * qz - qx * qw);
    const float R20 = 2.f * (qx * qz - qy * qw);
    const float R21 = 2.f * (qy * qz + qx * qw);
    const float R22 = 1.f - 2.f * (qx * qx + qy * qy);
    const float tx = t[0], ty = t[1], tz = t[2];

    const float px = pc[tid * 3 + 0], py = pc[tid * 3 + 1], pz = pc[tid * 3 + 2];
    const float cxp = R00 * px + R01 * py + R02 * pz + tx;
    const float cyp = R10 * px + R11 * py + R12 * pz + ty;
    const float czp = R20 * px + R21 * py + R22 * pz + tz;

    sd[tid] = czp;
    __syncthreads();

    // stable argsort rank: #{j : d_j < d_i || (d_j == d_i && j < i)}
    int rank = 0;
    const float4* sd4 = (const float4*)sd;
    #pragma unroll 4
    for (int j4 = 0; j4 < N_PTS / 4; ++j4) {
        const float4 v = sd4[j4];           // uniform addr -> LDS broadcast
        const int jb = j4 * 4;
        rank += (v.x < czp) || (v.x == czp && (jb + 0) < tid);
        rank += (v.y < czp) || (v.y == czp && (jb + 1) < tid);
        rank += (v.z < czp) || (v.z == czp && (jb + 2) < tid);
        rank += (v.w < czp) || (v.w == czp && (jb + 3) < tid);
    }

    const float fx = K[0], fy = K[4], cu = K[2], cv = K[5];
    const float al = alpha[tid];
    const float u  = cxp * fx / czp + cu;
    const float v  = cyp * fy / czp + cv;
    // prune threshold: zero contribution iff exp(pw)*al < 1/255, i.e.
    // pw < -log(255*al). 0.02 margin covers half-precision conic error.
    const float pt = -__logf(255.0f * al) - 0.02f;

    ws4[2 * rank]     = make_float4(u, v,
                                    pack2h(-0.5f * conic[tid * 3 + 0],
                                           -conic[tid * 3 + 1]),
                                    pt);
    ws4[2 * rank + 1] = make_float4(-0.5f * conic[tid * 3 + 2],
                                    pack2h(color[tid * 3 + 0], color[tid * 3 + 1]),
                                    pack2h(color[tid * 3 + 2], al),
                                    czp);
}

__global__ __launch_bounds__(512, 4) void raster_kernel(
    const float4* __restrict__ ws4,
    float* __restrict__ out)
{
    const int tid  = threadIdx.x;
    const int lane = tid & 63;
    // wave-uniform segment id in SGPR so point loads scalarize
    const int seg  = __builtin_amdgcn_readfirstlane(tid >> 6);

    // 64x2 pixel tile per block; each lane owns pixels (x,y) and (x,y+1)
    const int tx = blockIdx.x & 3;          // 4 tiles of 64 px across
    const int ty = blockIdx.x >> 2;         // 128 row-pairs
    const float up = (float)(tx * 64 + lane) + 0.5f;
    const float vp = (float)(ty * 2) + 0.5f;

    float T0 = 1.f, r0 = 0.f, g0 = 0.f, b0 = 0.f, d0 = 0.f, a0 = 0.f;
    float T1 = 1.f, r1 = 0.f, g1 = 0.f, b1 = 0.f, d1 = 0.f, a1 = 0.f;

    const int n0 = seg * SEG_LEN;
    #pragma unroll 4
    for (int i = 0; i < SEG_LEN; ++i) {
        const int n = n0 + i;                    // wave-uniform -> s_load
        const float4 p0 = ws4[2 * n];            // U V h2(A',B') PT
        const float4 p1 = ws4[2 * n + 1];        // C' h2(R,G) h2(Bc,AL) D
        const float dx  = up - p0.x;
        const float dy  = vp - p0.y;
        const float2 ab = unp2h(p0.z);           // A', B'
        const float Cc  = p1.x;                  // C'
        const float dx2 = dx * dx;
        const float bx  = ab.y * dx;             // B'*dx
        const float qa  = ab.x * dx2;            // A'*dx^2
        const float pw0 = fmaf(Cc, dy * dy, fmaf(bx, dy, qa));
        // pw(y+1) = pw(y) + 2*C'*dy + C' + B'*dx
        const float pw1 = pw0 + fmaf(Cc + Cc, dy, Cc + bx);
        if (__any(fmaxf(pw0, pw1) >= p0.w)) {
            const float2 rg = unp2h(p1.y);
            const float2 ba = unp2h(p1.z);
            const float AL  = ba.y;
            const float D   = p1.w;
            const float pa0 = __expf(pw0) * AL;
            const float pa1 = __expf(pw1) * AL;
            // pw < PT implies pa below 1/255, so the pa test stays exact
            const float e0 = (pa0 >= (1.0f / 255.0f)) ? fminf(pa0, 0.99f) : 0.f;
            const float e1 = (pa1 >= (1.0f / 255.0f)) ? fminf(pa1, 0.99f) : 0.f;
            const float w0 = e0 * T0, w1 = e1 * T1;
            r0 = fmaf(w0, rg.x, r0);  r1 = fmaf(w1, rg.x, r1);
            g0 = fmaf(w0, rg.y, g0);  g1 = fmaf(w1, rg.y, g1);
            b0 = fmaf(w0, ba.x, b0);  b1 = fmaf(w1, ba.x, b1);
            d0 = fmaf(w0, D, d0);     d1 = fmaf(w1, D, d1);
            a0 += w0;                 a1 += w1;
            T0 = fmaf(-e0, T0, T0);   T1 = fmaf(-e1, T1, T1);
        }
    }

    // ordered combine of 8 depth segments: (c,T) ⊕ (c',T') = (c + T c', T T')
    __shared__ float part[NSEG][12][64];
    part[seg][0][lane] = r0;  part[seg][1][lane] = g0;  part[seg][2][lane] = b0;
    part[seg][3][lane] = d0;  part[seg][4][lane] = a0;  part[seg][5][lane] = T0;
    part[seg][6][lane] = r1;  part[seg][7][lane] = g1;  part[seg][8][lane] = b1;
    part[seg][9][lane] = d1;  part[seg][10][lane] = a1; part[seg][11][lane] = T1;
    __syncthreads();

    if (tid < 128) {
        const int lx = tid & 63;
        const int sy = tid >> 6;
        const int o  = sy * 6;
        float c0 = part[0][o + 0][lx], c1 = part[0][o + 1][lx];
        float c2 = part[0][o + 2][lx], c3 = part[0][o + 3][lx];
        float c4 = part[0][o + 4][lx];
        float Tacc = part[0][o + 5][lx];
        #pragma unroll
        for (int s = 1; s < NSEG; ++s) {
            c0 = fmaf(Tacc, part[s][o + 0][lx], c0);
            c1 = fmaf(Tacc, part[s][o + 1][lx], c1);
            c2 = fmaf(Tacc, part[s][o + 2][lx], c2);
            c3 = fmaf(Tacc, part[s][o + 3][lx], c3);
            c4 = fmaf(Tacc, part[s][o + 4][lx], c4);
            Tacc *= part[s][o + 5][lx];
        }
        const int p = (ty * 2 + sy) * W_IMG + tx * 64 + lx;
        out[p * 3 + 0] = c0;
        out[p * 3 + 1] = c1;
        out[p * 3 + 2] = c2;
        out[NPIX * 3 + p] = c3;
        out[NPIX * 4 + p] = c4;
    }
}

extern "C" void kernel_launch(void* const* d_in, const int* in_sizes, int n_in,
                              void* d_out, int out_size, void* d_ws, size_t ws_size,
                              hipStream_t stream) {
    const float* pc    = (const float*)d_in[0];
    const float* q     = (const float*)d_in[1];
    const float* t     = (const float*)d_in[2];
    const float* K     = (const float*)d_in[3];
    const float* color = (const float*)d_in[4];
    const float* alpha = (const float*)d_in[5];
    const float* conic = (const float*)d_in[6];
    float* out  = (float*)d_out;
    float4* ws4 = (float4*)d_ws;

    prep_kernel<<<1, N_PTS, 0, stream>>>(pc, q, t, K, color, alpha, conic, ws4);
    raster_kernel<<<NPIX / 128, 512, 0, stream>>>(ws4, out);
}

// Round 6
// 31.715 us; speedup vs baseline: 1.1200x; 1.1200x over previous
//
#include <hip/hip_runtime.h>
#include <math.h>

#define N_PTS 512
#define W_IMG 256
#define H_IMG 256
#define NPIX (W_IMG * H_IMG)
#define TILE 8
#define TILES_X (W_IMG / TILE)          // 32
#define N_TILES (TILES_X * (H_IMG / TILE))  // 1024

// ws layout (float4 units):
//   [0 .. 3*512)  : sorted records, 3 float4 per point:
//       rec0 = (U, V, A'=-0.5a, B'=-b)
//       rec1 = (C'=-0.5c, PT, AL, D)
//       rec2 = (R, G, B, 0)
//   [3*512 .. 4*512) : aux bbox per sorted point: (U, V, rx, ry)

__global__ __launch_bounds__(N_PTS) void prep_kernel(
    const float* __restrict__ pc,      // N x 3
    const float* __restrict__ q,       // 1 x 4  (x,y,z,w)
    const float* __restrict__ t,       // 1 x 3
    const float* __restrict__ K,       // 3 x 3 row-major
    const float* __restrict__ color,   // N x 3
    const float* __restrict__ alpha,   // N
    const float* __restrict__ conic,   // N x 3 (a,b,c)
    float4* __restrict__ ws4)
{
    __shared__ float sd[N_PTS];
    const int tid = threadIdx.x;

    const float qx = q[0], qy = q[1], qz = q[2], qw = q[3];
    const float R00 = 1.f - 2.f * (qy * qy + qz * qz);
    const float R01 = 2.f * (qx * qy - qz * qw);
    const float R02 = 2.f * (qx * qz + qy * qw);
    const float R10 = 2.f * (qx * qy + qz * qw);
    const float R11 = 1.f - 2.f * (qx * qx + qz * qz);
    const float R12 = 2.f * (qy * qz - qx * qw);
    const float R20 = 2.f * (qx * qz - qy * qw);
    const float R21 = 2.f * (qy * qz + qx * qw);
    const float R22 = 1.f - 2.f * (qx * qx + qy * qy);
    const float tx = t[0], ty = t[1], tz = t[2];

    const float px = pc[tid * 3 + 0], py = pc[tid * 3 + 1], pz = pc[tid * 3 + 2];
    const float cxp = R00 * px + R01 * py + R02 * pz + tx;
    const float cyp = R10 * px + R11 * py + R12 * pz + ty;
    const float czp = R20 * px + R21 * py + R22 * pz + tz;

    sd[tid] = czp;
    __syncthreads();

    // stable argsort rank: #{j : d_j < d_i || (d_j == d_i && j < i)}
    int rank = 0;
    const float4* sd4 = (const float4*)sd;
    #pragma unroll 4
    for (int j4 = 0; j4 < N_PTS / 4; ++j4) {
        const float4 v = sd4[j4];           // uniform addr -> LDS broadcast
        const int jb = j4 * 4;
        rank += (v.x < czp) || (v.x == czp && (jb + 0) < tid);
        rank += (v.y < czp) || (v.y == czp && (jb + 1) < tid);
        rank += (v.z < czp) || (v.z == czp && (jb + 2) < tid);
        rank += (v.w < czp) || (v.w == czp && (jb + 3) < tid);
    }

    const float fx = K[0], fy = K[4], cu = K[2], cv = K[5];
    const float al = alpha[tid];
    const float u  = cxp * fx / czp + cu;
    const float v  = cyp * fy / czp + cv;
    // prune threshold: contribution zero iff exp(pw)*al < 1/255, i.e.
    // pw < -log(255*al). Margin 0.02 absorbs float rounding everywhere.
    const float tau = __logf(255.0f * al) + 0.02f;   // > 0 since al >= 0.1
    const float pt  = -tau;

    const float a = conic[tid * 3 + 0];
    const float b = conic[tid * 3 + 1];
    const float c = conic[tid * 3 + 2];
    // conservative bbox of the ellipse {0.5a dx^2 + b dxdy + 0.5c dy^2 = tau}:
    // rx = sqrt(2 tau c / (ac - b^2)), ry = sqrt(2 tau a / (ac - b^2)).
    // Outside the strip |dx|<=rx (or |dy|<=ry) implies pw < PT -> exact zero.
    const float det  = a * c - b * b;                // >= 0.84*ac > 0
    const float s    = 2.f * tau / det;
    const float rx   = sqrtf(s * c) * 1.001f + 0.02f;
    const float ry   = sqrtf(s * a) * 1.001f + 0.02f;

    ws4[3 * rank + 0] = make_float4(u, v, -0.5f * a, -b);
    ws4[3 * rank + 1] = make_float4(-0.5f * c, pt, al, czp);
    ws4[3 * rank + 2] = make_float4(color[tid * 3 + 0], color[tid * 3 + 1],
                                    color[tid * 3 + 2], 0.f);
    ws4[3 * N_PTS + rank] = make_float4(u, v, rx, ry);
}

__global__ __launch_bounds__(64) void raster_kernel(
    const float4* __restrict__ ws4,
    float* __restrict__ out)
{
    const int lane = threadIdx.x;
    const int tile = blockIdx.x;
    const int tx0 = (tile & (TILES_X - 1)) * TILE;
    const int ty0 = (tile / TILES_X) * TILE;
    const float xmin = (float)tx0 + 0.5f, xmax = (float)tx0 + (TILE - 0.5f);
    const float ymin = (float)ty0 + 0.5f, ymax = (float)ty0 + (TILE - 0.5f);

    __shared__ float4 rec[N_PTS][3];     // depth-ordered survivors, 24.5 KB

    const float4* __restrict__ aux = ws4 + 3 * N_PTS;
    int cnt = 0;
    #pragma unroll
    for (int i = 0; i < N_PTS / 64; ++i) {
        const int n = i * 64 + lane;
        const float4 bb = aux[n];                    // coalesced
        const bool keep = (bb.x + bb.z >= xmin) & (bb.x - bb.z <= xmax) &
                          (bb.y + bb.w >= ymin) & (bb.y - bb.w <= ymax);
        const unsigned long long m = __ballot(keep);
        if (keep) {
            const int pos = cnt + __popcll(m & ((1ull << lane) - 1ull));
            rec[pos][0] = ws4[3 * n + 0];
            rec[pos][1] = ws4[3 * n + 1];
            rec[pos][2] = ws4[3 * n + 2];
        }
        cnt += __popcll(m);
    }
    __syncthreads();                                 // single wave: cheap

    const float up = (float)(tx0 + (lane & 7)) + 0.5f;
    const float vp = (float)(ty0 + (lane >> 3)) + 0.5f;

    float T = 1.f, rr = 0.f, gg = 0.f, bl = 0.f, dd = 0.f, aa = 0.f;

    #pragma unroll 2
    for (int j = 0; j < cnt; ++j) {
        const float4 p0 = rec[j][0];                 // uniform -> LDS broadcast
        const float4 p1 = rec[j][1];
        const float dx = up - p0.x;
        const float dy = vp - p0.y;
        const float pw = fmaf(p0.z, dx * dx,
                         fmaf(p1.x, dy * dy, p0.w * (dx * dy)));
        if (__any(pw >= p1.y)) {
            const float pa = __expf(pw) * p1.z;
            // pw < PT implies pa < e^-0.02/255 < 1/255: pa test stays exact
            const float e = (pa >= (1.0f / 255.0f)) ? fminf(pa, 0.99f) : 0.f;
            const float w = e * T;
            const float4 p2 = rec[j][2];
            rr = fmaf(w, p2.x, rr);
            gg = fmaf(w, p2.y, gg);
            bl = fmaf(w, p2.z, bl);
            dd = fmaf(w, p1.w, dd);
            aa += w;
            T = fmaf(-e, T, T);                      // T *= (1 - e)
        }
    }

    const int p = (ty0 + (lane >> 3)) * W_IMG + tx0 + (lane & 7);
    out[p * 3 + 0] = rr;
    out[p * 3 + 1] = gg;
    out[p * 3 + 2] = bl;
    out[NPIX * 3 + p] = dd;
    out[NPIX * 4 + p] = aa;
}

extern "C" void kernel_launch(void* const* d_in, const int* in_sizes, int n_in,
                              void* d_out, int out_size, void* d_ws, size_t ws_size,
                              hipStream_t stream) {
    const float* pc    = (const float*)d_in[0];
    const float* q     = (const float*)d_in[1];
    const float* t     = (const float*)d_in[2];
    const float* K     = (const float*)d_in[3];
    const float* color = (const float*)d_in[4];
    const float* alpha = (const float*)d_in[5];
    const float* conic = (const float*)d_in[6];
    float* out  = (float*)d_out;
    float4* ws4 = (float4*)d_ws;

    prep_kernel<<<1, N_PTS, 0, stream>>>(pc, q, t, K, color, alpha, conic, ws4);
    raster_kernel<<<N_TILES, 64, 0, stream>>>(ws4, out);
}

// Round 7
// 17.385 us; speedup vs baseline: 2.0432x; 1.8243x over previous
//
#include <hip/hip_runtime.h>
#include <math.h>

#define N_PTS 512
#define W_IMG 256
#define H_IMG 256
#define NPIX (W_IMG * H_IMG)
#define TILE 8
#define TILES_X (W_IMG / TILE)              // 32
#define N_TILES (TILES_X * (H_IMG / TILE))  // 1024

// One fused kernel: each block owns one 8x8 tile. It re-transforms all 512
// points (coalesced, L2-resident inputs, redundant across blocks but trivial),
// culls by conservative ellipse bbox, compacts survivors into LDS, sorts them
// locally by (depth, original index) — the restriction of the global stable
// argsort — then composites front-to-back.

__global__ __launch_bounds__(64) void fused_raster_kernel(
    const float* __restrict__ pc,      // N x 3
    const float* __restrict__ q,       // 1 x 4  (x,y,z,w)
    const float* __restrict__ t,       // 1 x 3
    const float* __restrict__ K,       // 3 x 3 row-major
    const float* __restrict__ color,   // N x 3
    const float* __restrict__ alpha,   // N
    const float* __restrict__ conic,   // N x 3 (a,b,c)
    float* __restrict__ out)
{
    const int lane = threadIdx.x;
    const int tile = blockIdx.x;
    const int tx0 = (tile & (TILES_X - 1)) * TILE;
    const int ty0 = (tile / TILES_X) * TILE;
    const float xmin = (float)tx0 + 0.5f, xmax = (float)tx0 + (TILE - 0.5f);
    const float ymin = (float)ty0 + 0.5f, ymax = (float)ty0 + (TILE - 0.5f);

    // camera scalars (uniform -> s_loads)
    const float qx = q[0], qy = q[1], qz = q[2], qw = q[3];
    const float R00 = 1.f - 2.f * (qy * qy + qz * qz);
    const float R01 = 2.f * (qx * qy - qz * qw);
    const float R02 = 2.f * (qx * qz + qy * qw);
    const float R10 = 2.f * (qx * qy + qz * qw);
    const float R11 = 1.f - 2.f * (qx * qx + qz * qz);
    const float R12 = 2.f * (qy * qz - qx * qw);
    const float R20 = 2.f * (qx * qz - qy * qw);
    const float R21 = 2.f * (qy * qz + qx * qw);
    const float R22 = 1.f - 2.f * (qx * qx + qy * qy);
    const float tcx = t[0], tcy = t[1], tcz = t[2];
    const float fx = K[0], fy = K[4], cu = K[2], cv = K[5];

    __shared__ float4 rec[N_PTS][3];    // survivors, 24.5 KB
    __shared__ float  sdep[N_PTS];
    __shared__ int    sidx[N_PTS];
    __shared__ int    sperm[N_PTS];

    int cnt = 0;
    #pragma unroll
    for (int i = 0; i < N_PTS / 64; ++i) {
        const int n = i * 64 + lane;
        const float px = pc[n * 3 + 0], py = pc[n * 3 + 1], pz = pc[n * 3 + 2];
        const float cxp = R00 * px + R01 * py + R02 * pz + tcx;
        const float cyp = R10 * px + R11 * py + R12 * pz + tcy;
        const float czp = R20 * px + R21 * py + R22 * pz + tcz;
        const float u = cxp * fx / czp + cu;
        const float v = cyp * fy / czp + cv;

        const float al = alpha[n];
        const float a = conic[n * 3 + 0];
        const float b = conic[n * 3 + 1];
        const float c = conic[n * 3 + 2];
        // contribution is exactly zero iff exp(pw)*al < 1/255, i.e.
        // pw < -log(255*al). 0.02 margin absorbs float rounding.
        const float tau = __logf(255.0f * al) + 0.02f;   // > 0 (al >= 0.1)
        const float pt  = -tau;
        // conservative bbox of {0.5a dx^2 + b dxdy + 0.5c dy^2 = tau}:
        const float det = a * c - b * b;                 // >= 0.84*ac > 0
        const float s   = 2.f * tau / det;
        const float rx  = sqrtf(s * c) * 1.001f + 0.02f;
        const float ry  = sqrtf(s * a) * 1.001f + 0.02f;

        const bool keep = (u + rx >= xmin) & (u - rx <= xmax) &
                          (v + ry >= ymin) & (v - ry <= ymax);
        const unsigned long long m = __ballot(keep);
        if (keep) {
            const int pos = cnt + __popcll(m & ((1ull << lane) - 1ull));
            rec[pos][0] = make_float4(u, v, -0.5f * a, -b);
            rec[pos][1] = make_float4(-0.5f * c, pt, al, czp);
            rec[pos][2] = make_float4(color[n * 3 + 0], color[n * 3 + 1],
                                      color[n * 3 + 2], 0.f);
            sdep[pos] = czp;
            sidx[pos] = n;
        }
        cnt += __popcll(m);
    }
    __syncthreads();

    // local stable rank-sort by (depth, original idx) -> permutation
    for (int e = lane; e < cnt; e += 64) {
        const float de = sdep[e];
        const int   ie = sidx[e];
        int rk = 0;
        for (int j = 0; j < cnt; ++j) {
            const float dj = sdep[j];          // uniform addr -> broadcast
            const int   ij = sidx[j];
            rk += (dj < de) || (dj == de && ij < ie);
        }
        sperm[rk] = e;
    }
    __syncthreads();

    const float up = (float)(tx0 + (lane & 7)) + 0.5f;
    const float vp = (float)(ty0 + (lane >> 3)) + 0.5f;

    float T = 1.f, rr = 0.f, gg = 0.f, bl = 0.f, dd = 0.f, aa = 0.f;

    for (int j = 0; j < cnt; ++j) {
        const int e = sperm[j];                // uniform -> broadcast
        const float4 p0 = rec[e][0];
        const float4 p1 = rec[e][1];
        const float dx = up - p0.x;
        const float dy = vp - p0.y;
        const float pw = fmaf(p0.z, dx * dx,
                         fmaf(p1.x, dy * dy, p0.w * (dx * dy)));
        if (__any(pw >= p1.y)) {
            const float pa = __expf(pw) * p1.z;
            // pw < PT implies pa < e^-0.02/255 < 1/255: pa test stays exact
            const float e0 = (pa >= (1.0f / 255.0f)) ? fminf(pa, 0.99f) : 0.f;
            const float w = e0 * T;
            const float4 p2 = rec[e][2];
            rr = fmaf(w, p2.x, rr);
            gg = fmaf(w, p2.y, gg);
            bl = fmaf(w, p2.z, bl);
            dd = fmaf(w, p1.w, dd);
            aa += w;
            T = fmaf(-e0, T, T);               // T *= (1 - e0)
        }
    }

    const int p = (ty0 + (lane >> 3)) * W_IMG + tx0 + (lane & 7);
    out[p * 3 + 0] = rr;
    out[p * 3 + 1] = gg;
    out[p * 3 + 2] = bl;
    out[NPIX * 3 + p] = dd;
    out[NPIX * 4 + p] = aa;
}

extern "C" void kernel_launch(void* const* d_in, const int* in_sizes, int n_in,
                              void* d_out, int out_size, void* d_ws, size_t ws_size,
                              hipStream_t stream) {
    const float* pc    = (const float*)d_in[0];
    const float* q     = (const float*)d_in[1];
    const float* t     = (const float*)d_in[2];
    const float* K     = (const float*)d_in[3];
    const float* color = (const float*)d_in[4];
    const float* alpha = (const float*)d_in[5];
    const float* conic = (const float*)d_in[6];
    float* out = (float*)d_out;

    fused_raster_kernel<<<N_TILES, 64, 0, stream>>>(pc, q, t, K, color,
                                                    alpha, conic, out);
}

// Round 8
// 13.669 us; speedup vs baseline: 2.5988x; 1.2719x over previous
//
#include <hip/hip_runtime.h>
#include <math.h>

#define N_PTS 512
#define W_IMG 256
#define H_IMG 256
#define NPIX (W_IMG * H_IMG)
#define TILE 8
#define TILES_X (W_IMG / TILE)              // 32
#define N_TILES (TILES_X * (H_IMG / TILE))  // 1024
#define NTHR 256
#define NSEG 4                              // composite split across 4 waves

// One fused kernel, one 8x8 tile per 256-thread block:
//   phase 1: all threads transform+cull the 512 points (2 iters), compact
//            survivors into LDS via atomicAdd (order fixed later by sort)
//   phase 2: local stable rank-sort by (depth, original idx)  — restriction
//            of the global stable argsort, so compositing order is exact
//   phase 3: each wave composites one depth segment of survivors for all
//            64 pixels; (c,T) monoid combine across waves in LDS
//   phase 4: wave 0 folds segments front-to-back and writes out

__global__ __launch_bounds__(NTHR) void fused_raster_kernel(
    const float* __restrict__ pc,      // N x 3
    const float* __restrict__ q,       // 1 x 4  (x,y,z,w)
    const float* __restrict__ t,       // 1 x 3
    const float* __restrict__ K,       // 3 x 3 row-major
    const float* __restrict__ color,   // N x 3
    const float* __restrict__ alpha,   // N
    const float* __restrict__ conic,   // N x 3 (a,b,c)
    float* __restrict__ out)
{
    const int tid  = threadIdx.x;
    const int lane = tid & 63;
    const int wv   = __builtin_amdgcn_readfirstlane(tid >> 6);

    const int tile = blockIdx.x;
    const int tx0 = (tile & (TILES_X - 1)) * TILE;
    const int ty0 = (tile / TILES_X) * TILE;
    const float xmin = (float)tx0 + 0.5f, xmax = (float)tx0 + (TILE - 0.5f);
    const float ymin = (float)ty0 + 0.5f, ymax = (float)ty0 + (TILE - 0.5f);

    // camera scalars (uniform -> s_loads)
    const float qx = q[0], qy = q[1], qz = q[2], qw = q[3];
    const float R00 = 1.f - 2.f * (qy * qy + qz * qz);
    const float R01 = 2.f * (qx * qy - qz * qw);
    const float R02 = 2.f * (qx * qz + qy * qw);
    const float R10 = 2.f * (qx * qy + qz * qw);
    const float R11 = 1.f - 2.f * (qx * qx + qz * qz);
    const float R12 = 2.f * (qy * qz - qx * qw);
    const float R20 = 2.f * (qx * qz - qy * qw);
    const float R21 = 2.f * (qy * qz + qx * qw);
    const float R22 = 1.f - 2.f * (qx * qx + qy * qy);
    const float tcx = t[0], tcy = t[1], tcz = t[2];
    const float fx = K[0], fy = K[4], cu = K[2], cv = K[5];

    __shared__ float4 rec[N_PTS][3];        // survivors, 24.5 KB
    __shared__ float  sdep[N_PTS];
    __shared__ int    sidx[N_PTS];
    __shared__ int    sperm[N_PTS];
    __shared__ float  part[NSEG][6][64];
    __shared__ int    scnt;

    if (tid == 0) scnt = 0;
    __syncthreads();

    #pragma unroll
    for (int i = 0; i < N_PTS / NTHR; ++i) {
        const int n = i * NTHR + tid;
        const float px = pc[n * 3 + 0], py = pc[n * 3 + 1], pz = pc[n * 3 + 2];
        const float cxp = R00 * px + R01 * py + R02 * pz + tcx;
        const float cyp = R10 * px + R11 * py + R12 * pz + tcy;
        const float czp = R20 * px + R21 * py + R22 * pz + tcz;
        const float u = cxp * fx / czp + cu;
        const float v = cyp * fy / czp + cv;

        const float al = alpha[n];
        const float a = conic[n * 3 + 0];
        const float b = conic[n * 3 + 1];
        const float c = conic[n * 3 + 2];
        // contribution exactly zero iff exp(pw)*al < 1/255, i.e.
        // pw < -log(255*al). 0.02 margin absorbs float rounding.
        const float tau = __logf(255.0f * al) + 0.02f;   // > 0 (al >= 0.1)
        const float pt  = -tau;
        // conservative bbox of {0.5a dx^2 + b dxdy + 0.5c dy^2 = tau}:
        const float det = a * c - b * b;                 // >= 0.84*ac > 0
        const float s   = 2.f * tau / det;
        const float rx  = sqrtf(s * c) * 1.001f + 0.02f;
        const float ry  = sqrtf(s * a) * 1.001f + 0.02f;

        const bool keep = (u + rx >= xmin) & (u - rx <= xmax) &
                          (v + ry >= ymin) & (v - ry <= ymax);
        if (keep) {
            const int pos = atomicAdd(&scnt, 1);         // order fixed by sort
            rec[pos][0] = make_float4(u, v, -0.5f * a, -b);
            rec[pos][1] = make_float4(-0.5f * c, pt, al, czp);
            rec[pos][2] = make_float4(color[n * 3 + 0], color[n * 3 + 1],
                                      color[n * 3 + 2], 0.f);
            sdep[pos] = czp;
            sidx[pos] = n;
        }
    }
    __syncthreads();
    const int cnt = scnt;

    // local stable rank-sort by (depth, original idx) -> permutation
    for (int e = tid; e < cnt; e += NTHR) {
        const float de = sdep[e];
        const int   ie = sidx[e];
        int rk = 0;
        for (int j = 0; j < cnt; ++j) {
            const float dj = sdep[j];          // uniform addr -> broadcast
            const int   ij = sidx[j];
            rk += (dj < de) || (dj == de && ij < ie);
        }
        sperm[rk] = e;
    }
    __syncthreads();

    // composite my wave's depth segment for all 64 pixels (branchless body)
    const float up = (float)(tx0 + (lane & 7)) + 0.5f;
    const float vp = (float)(ty0 + (lane >> 3)) + 0.5f;

    float T = 1.f, rr = 0.f, gg = 0.f, bl = 0.f, dd = 0.f, aa = 0.f;
    const int j0 = (cnt * wv) >> 2;
    const int j1 = (cnt * (wv + 1)) >> 2;

    for (int j = j0; j < j1; ++j) {
        const int e = sperm[j];                // uniform -> broadcast
        const float4 p0 = rec[e][0];
        const float4 p1 = rec[e][1];
        const float4 p2 = rec[e][2];
        const float dx = up - p0.x;
        const float dy = vp - p0.y;
        const float pw = fmaf(p0.z, dx * dx,
                         fmaf(p1.x, dy * dy, p0.w * (dx * dy)));
        const float pa = __expf(pw) * p1.z;
        // reference: weight zero iff pa < 1/255 (pw<PT branch folded in: the
        // exp path is exact everywhere since pa-test alone decides)
        const float e0 = (pa >= (1.0f / 255.0f)) ? fminf(pa, 0.99f) : 0.f;
        const float w = e0 * T;
        rr = fmaf(w, p2.x, rr);
        gg = fmaf(w, p2.y, gg);
        bl = fmaf(w, p2.z, bl);
        dd = fmaf(w, p1.w, dd);
        aa += w;
        T = fmaf(-e0, T, T);                   // T *= (1 - e0)
    }

    part[wv][0][lane] = rr;  part[wv][1][lane] = gg;  part[wv][2][lane] = bl;
    part[wv][3][lane] = dd;  part[wv][4][lane] = aa;  part[wv][5][lane] = T;
    __syncthreads();

    if (tid < 64) {
        float c0 = part[0][0][tid], c1 = part[0][1][tid], c2 = part[0][2][tid];
        float c3 = part[0][3][tid], c4 = part[0][4][tid];
        float Tacc = part[0][5][tid];
        #pragma unroll
        for (int s = 1; s < NSEG; ++s) {
            c0 = fmaf(Tacc, part[s][0][tid], c0);
            c1 = fmaf(Tacc, part[s][1][tid], c1);
            c2 = fmaf(Tacc, part[s][2][tid], c2);
            c3 = fmaf(Tacc, part[s][3][tid], c3);
            c4 = fmaf(Tacc, part[s][4][tid], c4);
            Tacc *= part[s][5][tid];
        }
        const int p = (ty0 + (tid >> 3)) * W_IMG + tx0 + (tid & 7);
        out[p * 3 + 0] = c0;
        out[p * 3 + 1] = c1;
        out[p * 3 + 2] = c2;
        out[NPIX * 3 + p] = c3;
        out[NPIX * 4 + p] = c4;
    }
}

extern "C" void kernel_launch(void* const* d_in, const int* in_sizes, int n_in,
                              void* d_out, int out_size, void* d_ws, size_t ws_size,
                              hipStream_t stream) {
    const float* pc    = (const float*)d_in[0];
    const float* q     = (const float*)d_in[1];
    const float* t     = (const float*)d_in[2];
    const float* K     = (const float*)d_in[3];
    const float* color = (const float*)d_in[4];
    const float* alpha = (const float*)d_in[5];
    const float* conic = (const float*)d_in[6];
    float* out = (float*)d_out;

    fused_raster_kernel<<<N_TILES, NTHR, 0, stream>>>(pc, q, t, K, color,
                                                      alpha, conic, out);
}

// Round 9
// 13.266 us; speedup vs baseline: 2.6777x; 1.0304x over previous
//
#include <hip/hip_runtime.h>
#include <math.h>

#define N_PTS 512
#define W_IMG 256
#define H_IMG 256
#define NPIX (W_IMG * H_IMG)
#define TILE 8
#define TILES_X (W_IMG / TILE)              // 32
#define N_TILES (TILES_X * (H_IMG / TILE))  // 1024
#define NTHR 512
#define NSEG 8                              // composite split across 8 waves

// One fused kernel, one 8x8 tile per 512-thread block:
//   phase 1: one point per thread: transform + cull; per-wave ballot
//            compaction into LDS (one atomic per wave)
//   phase 2: local stable rank-sort by (depth, original idx) — restriction
//            of the global stable argsort, so compositing order is exact
//   phase 3: each of 8 waves composites one depth segment for all 64 px
//   phase 4: (c,T) monoid fold across segments by wave 0, write out
// part[] reuses rec[]'s LDS after a barrier (keeps LDS ~30.7 KB).

__global__ __launch_bounds__(NTHR) void fused_raster_kernel(
    const float* __restrict__ pc,      // N x 3
    const float* __restrict__ q,       // 1 x 4  (x,y,z,w)
    const float* __restrict__ t,       // 1 x 3
    const float* __restrict__ K,       // 3 x 3 row-major
    const float* __restrict__ color,   // N x 3
    const float* __restrict__ alpha,   // N
    const float* __restrict__ conic,   // N x 3 (a,b,c)
    float* __restrict__ out)
{
    const int tid  = threadIdx.x;
    const int lane = tid & 63;
    const int wv   = __builtin_amdgcn_readfirstlane(tid >> 6);

    const int tile = blockIdx.x;
    const int tx0 = (tile & (TILES_X - 1)) * TILE;
    const int ty0 = (tile / TILES_X) * TILE;
    const float xmin = (float)tx0 + 0.5f, xmax = (float)tx0 + (TILE - 0.5f);
    const float ymin = (float)ty0 + 0.5f, ymax = (float)ty0 + (TILE - 0.5f);

    // issue my point's loads first (independent of camera scalars)
    const int n = tid;                       // NTHR == N_PTS
    const float px = pc[n * 3 + 0], py = pc[n * 3 + 1], pz = pc[n * 3 + 2];
    const float al = alpha[n];
    const float a  = conic[n * 3 + 0];
    const float b  = conic[n * 3 + 1];
    const float c  = conic[n * 3 + 2];
    const float cr = color[n * 3 + 0], cg = color[n * 3 + 1],
                cb = color[n * 3 + 2];

    // camera scalars (uniform -> s_loads)
    const float qx = q[0], qy = q[1], qz = q[2], qw = q[3];
    const float R00 = 1.f - 2.f * (qy * qy + qz * qz);
    const float R01 = 2.f * (qx * qy - qz * qw);
    const float R02 = 2.f * (qx * qz + qy * qw);
    const float R10 = 2.f * (qx * qy + qz * qw);
    const float R11 = 1.f - 2.f * (qx * qx + qz * qz);
    const float R12 = 2.f * (qy * qz - qx * qw);
    const float R20 = 2.f * (qx * qz - qy * qw);
    const float R21 = 2.f * (qy * qz + qx * qw);
    const float R22 = 1.f - 2.f * (qx * qx + qy * qy);
    const float tcx = t[0], tcy = t[1], tcz = t[2];
    const float fx = K[0], fy = K[4], cu = K[2], cv = K[5];

    __shared__ float4 rec[N_PTS][3];        // survivors, 24.5 KB (reused)
    __shared__ float  sdep[N_PTS];
    __shared__ int    sidx[N_PTS];
    __shared__ int    sperm[N_PTS];
    __shared__ int    scnt;

    if (tid == 0) scnt = 0;
    __syncthreads();

    // phase 1: transform + cull (one point per thread)
    const float cxp = R00 * px + R01 * py + R02 * pz + tcx;
    const float cyp = R10 * px + R11 * py + R12 * pz + tcy;
    const float czp = R20 * px + R21 * py + R22 * pz + tcz;
    const float u = cxp * fx / czp + cu;
    const float v = cyp * fy / czp + cv;

    // contribution exactly zero iff exp(pw)*al < 1/255, i.e. pw < -log(255*al)
    const float tau = __logf(255.0f * al) + 0.02f;   // > 0 (al >= 0.1)
    const float pt  = -tau;
    // conservative bbox of {0.5a dx^2 + b dxdy + 0.5c dy^2 = tau}
    const float det = a * c - b * b;                 // >= 0.84*ac > 0
    const float s   = 2.f * tau / det;
    const float rx  = sqrtf(s * c) * 1.001f + 0.02f;
    const float ry  = sqrtf(s * a) * 1.001f + 0.02f;

    const bool keep = (u + rx >= xmin) & (u - rx <= xmax) &
                      (v + ry >= ymin) & (v - ry <= ymax);
    {
        const unsigned long long m = __ballot(keep);
        const int nk = __popcll(m);
        int base = 0;
        if (lane == 0 && nk) base = atomicAdd(&scnt, nk);
        base = __shfl(base, 0);
        if (keep) {
            const int pos = base + __popcll(m & ((1ull << lane) - 1ull));
            rec[pos][0] = make_float4(u, v, -0.5f * a, -b);
            rec[pos][1] = make_float4(-0.5f * c, pt, al, czp);
            rec[pos][2] = make_float4(cr, cg, cb, 0.f);
            sdep[pos] = czp;
            sidx[pos] = n;
        }
    }
    __syncthreads();
    const int cnt = scnt;

    // phase 2: stable rank-sort by (depth, original idx) — one parallel pass
    if (tid < cnt) {
        const float de = sdep[tid];
        const int   ie = sidx[tid];
        int rk = 0;
        for (int j = 0; j < cnt; ++j) {
            const float dj = sdep[j];          // uniform addr -> broadcast
            const int   ij = sidx[j];
            rk += (dj < de) || (dj == de && ij < ie);
        }
        sperm[rk] = tid;
    }
    __syncthreads();

    // phase 3: composite my wave's depth segment (branchless body)
    const float up = (float)(tx0 + (lane & 7)) + 0.5f;
    const float vp = (float)(ty0 + (lane >> 3)) + 0.5f;

    float T = 1.f, rr = 0.f, gg = 0.f, bl = 0.f, dd = 0.f, aa = 0.f;
    const int j0 = (cnt * wv) >> 3;
    const int j1 = (cnt * (wv + 1)) >> 3;

    for (int j = j0; j < j1; ++j) {
        const int e = sperm[j];                // uniform -> broadcast
        const float4 p0 = rec[e][0];
        const float4 p1 = rec[e][1];
        const float4 p2 = rec[e][2];
        const float dx = up - p0.x;
        const float dy = vp - p0.y;
        const float pw = fmaf(p0.z, dx * dx,
                         fmaf(p1.x, dy * dy, p0.w * (dx * dy)));
        const float pa = __expf(pw) * p1.z;
        // weight zero iff pa < 1/255 (pw<PT pre-branch folded in; exact)
        const float e0 = (pa >= (1.0f / 255.0f)) ? fminf(pa, 0.99f) : 0.f;
        const float w = e0 * T;
        rr = fmaf(w, p2.x, rr);
        gg = fmaf(w, p2.y, gg);
        bl = fmaf(w, p2.z, bl);
        dd = fmaf(w, p1.w, dd);
        aa += w;
        T = fmaf(-e0, T, T);                   // T *= (1 - e0)
    }

    __syncthreads();                           // rec no longer needed
    float* part = (float*)rec;                 // [NSEG][6][64] view, 12 KB
    part[(wv * 6 + 0) * 64 + lane] = rr;
    part[(wv * 6 + 1) * 64 + lane] = gg;
    part[(wv * 6 + 2) * 64 + lane] = bl;
    part[(wv * 6 + 3) * 64 + lane] = dd;
    part[(wv * 6 + 4) * 64 + lane] = aa;
    part[(wv * 6 + 5) * 64 + lane] = T;
    __syncthreads();

    // phase 4: ordered fold (front-to-back) + store
    if (tid < 64) {
        float c0 = part[0 * 64 + tid], c1 = part[1 * 64 + tid];
        float c2 = part[2 * 64 + tid], c3 = part[3 * 64 + tid];
        float c4 = part[4 * 64 + tid];
        float Tacc = part[5 * 64 + tid];
        #pragma unroll
        for (int sgi = 1; sgi < NSEG; ++sgi) {
            const float* ps = part + sgi * 6 * 64;
            c0 = fmaf(Tacc, ps[0 * 64 + tid], c0);
            c1 = fmaf(Tacc, ps[1 * 64 + tid], c1);
            c2 = fmaf(Tacc, ps[2 * 64 + tid], c2);
            c3 = fmaf(Tacc, ps[3 * 64 + tid], c3);
            c4 = fmaf(Tacc, ps[4 * 64 + tid], c4);
            Tacc *= ps[5 * 64 + tid];
        }
        const int p = (ty0 + (tid >> 3)) * W_IMG + tx0 + (tid & 7);
        out[p * 3 + 0] = c0;
        out[p * 3 + 1] = c1;
        out[p * 3 + 2] = c2;
        out[NPIX * 3 + p] = c3;
        out[NPIX * 4 + p] = c4;
    }
}

extern "C" void kernel_launch(void* const* d_in, const int* in_sizes, int n_in,
                              void* d_out, int out_size, void* d_ws, size_t ws_size,
                              hipStream_t stream) {
    const float* pc    = (const float*)d_in[0];
    const float* q     = (const float*)d_in[1];
    const float* t     = (const float*)d_in[2];
    const float* K     = (const float*)d_in[3];
    const float* color = (const float*)d_in[4];
    const float* alpha = (const float*)d_in[5];
    const float* conic = (const float*)d_in[6];
    float* out = (float*)d_out;

    fused_raster_kernel<<<N_TILES, NTHR, 0, stream>>>(pc, q, t, K, color,
                                                      alpha, conic, out);
}